// Round 3
// baseline (389.352 us; speedup 1.0000x reference)
//
#include <hip/hip_runtime.h>
#include <hip/hip_bf16.h>
#include <float.h>

#define NN 2048
#define HH 16
#define DDIM 64
#define QB 32
#define KB 64
#define SP 68   // ssh pitch in floats (padded to break bank alignment)

typedef __bf16 bf16x8 __attribute__((ext_vector_type(8)));
typedef __bf16 bf16x4 __attribute__((ext_vector_type(4)));
typedef float f32x4 __attribute__((ext_vector_type(4)));

// Raw barrier: LDS-writes visible, but outstanding GLOBAL loads (prefetch)
// are NOT drained (unlike __syncthreads' vmcnt(0) drain).
__device__ __forceinline__ void barw() {
  __builtin_amdgcn_sched_barrier(0);
  asm volatile("s_waitcnt lgkmcnt(0)" ::: "memory");
  __builtin_amdgcn_s_barrier();
  __builtin_amdgcn_sched_barrier(0);
}

// Flash-style fused attention with prev_attn + bias + bool-mask + causal.
// R3: unpaired grid 64x16 = 1024 blocks -> 4 blocks/CU (was 2). Causal
// imbalance balanced by qt mapping: CU slot rounds get complementary qt.
// Block: 256 threads = 4 waves. Wave w: rows (w&1)*16, kv-half (w>>1)*32.
__global__ __launch_bounds__(256, 4) void attend_fused(
    const float* __restrict__ qg, const float* __restrict__ kg,
    const float* __restrict__ vg, const unsigned int* __restrict__ maskw,
    const float* __restrict__ biasg, const float* __restrict__ prevg,
    float* __restrict__ outg)
{
  __shared__ char  ksh[KB * 128]   __attribute__((aligned(16))); // [kv][d] bf16, swizzled
  __shared__ char  vsh[DDIM * 128] __attribute__((aligned(16))); // [d][kv] bf16, swizzled
  __shared__ float ssh[QB * SP]    __attribute__((aligned(16))); // padded f32 S tile
  __shared__ char  psh[QB * 128]   __attribute__((aligned(16))); // [r][kv] bf16, swizzled
  __shared__ float scale_s[QB];
  __shared__ float m_s[QB], l_s[QB];
  __shared__ float vmean_s[DDIM];

  const int t    = threadIdx.x;
  const int lane = t & 63;
  const int w    = t >> 6;
  const int x    = blockIdx.x;
  const int h    = blockIdx.y;
  // balanced causal mapping: bit 2 of h == bit 8 of flat bid; CU slot rounds
  // {bid, bid+256, bid+512, bid+768} alternate it -> per-CU work ~constant.
  const int qt   = ((h >> 2) & 1) ? x : (63 - x);

  // --- mask element-width detection: 4-byte (int32/float32 bool) vs 1-byte ---
  unsigned int mwrd = maskw[t & 255];
  const int mask4 = __syncthreads_and(mwrd == 0u || mwrd == 1u || mwrd == 0x3F800000u);

  const int r0  = (w & 1) * 16;   // wave's row strip inside 32-row q-tile
  const int c0  = (w >> 1) * 32;  // wave's kv half inside 64-col tile
  const int lhi = lane >> 4;
  const int llo = lane & 15;
  const int sr  = t >> 3;         // softmax-phase row 0..31
  const int sc  = (t & 7) * 8;    // softmax-phase col base

  const int qrow0 = qt * QB;

  // --- Q fragments, scale (1/8, exact) folded in ---
  bf16x8 aq[2];
  {
    const int row = qrow0 + r0 + llo;
    const float* qp = qg + ((size_t)(h * NN + row)) * DDIM + lhi * 8;
#pragma unroll
    for (int ks = 0; ks < 2; ++ks) {
      float4 f0 = *(const float4*)(qp + ks * 32);
      float4 f1 = *(const float4*)(qp + ks * 32 + 4);
      bf16x8 a;
      a[0] = (__bf16)(f0.x * 0.125f); a[1] = (__bf16)(f0.y * 0.125f);
      a[2] = (__bf16)(f0.z * 0.125f); a[3] = (__bf16)(f0.w * 0.125f);
      a[4] = (__bf16)(f1.x * 0.125f); a[5] = (__bf16)(f1.y * 0.125f);
      a[6] = (__bf16)(f1.z * 0.125f); a[7] = (__bf16)(f1.w * 0.125f);
      aq[ks] = a;
    }
  }

  f32x4 oacc[4];
#pragma unroll
  for (int i = 0; i < 4; ++i) { f32x4 z = {0.f, 0.f, 0.f, 0.f}; oacc[i] = z; }
  float m_r = -FLT_MAX, l_r = 0.f;
  const int irow = qrow0 + sr;

  // ---- prefetch registers ----
  float4 kpre[4], vpre[4];
  float4 ppre0, ppre1, bpre0, bpre1;
  uint4  mq0, mq1;

  auto issueKV = [&](int kv0) {
#pragma unroll
    for (int e = 0; e < 4; ++e) {
      const int f4  = t + e * 256;
      const int row = f4 >> 4;
      const int cb  = (f4 & 15) * 4;
      const size_t gofs = ((size_t)(h * NN + kv0 + row)) * DDIM + cb;
      kpre[e] = *(const float4*)(kg + gofs);
      vpre[e] = *(const float4*)(vg + gofs);
    }
  };
  auto issuePB = [&](int kv0) {
    const size_t base = ((size_t)(h * NN) + irow) * NN + kv0 + sc;
    ppre0 = *(const float4*)(prevg + base);
    ppre1 = *(const float4*)(prevg + base + 4);
    bpre0 = *(const float4*)(biasg + base);
    bpre1 = *(const float4*)(biasg + base + 4);
    const size_t midx = (size_t)irow * NN + kv0 + sc;
    if (mask4) {
      mq0 = *(const uint4*)(maskw + midx);
      mq1 = *(const uint4*)(maskw + midx + 4);
    } else {
      const unsigned int* mp = (const unsigned int*)((const unsigned char*)maskw + midx);
      mq0.x = mp[0]; mq0.y = mp[1];
    }
  };

  const int Tq = (qrow0 + QB - 1) / KB + 1;
  issueKV(0);
  issuePB(0);

  for (int tt = 0; tt < Tq; ++tt) {
    const int kv0 = tt * KB;
    // ---- phase 1: stage K (row-major) and V (transposed) from prefetch regs ----
#pragma unroll
    for (int e = 0; e < 4; ++e) {
      const int f4  = t + e * 256;       // 0..1023 float4s
      const int row = f4 >> 4;           // kv index in tile
      const int cb  = (f4 & 15) * 4;     // d base
      float4 kf = kpre[e];
      bf16x4 kb4;
      kb4[0] = (__bf16)kf.x; kb4[1] = (__bf16)kf.y;
      kb4[2] = (__bf16)kf.z; kb4[3] = (__bf16)kf.w;
      *(bf16x4*)(ksh + (((row << 7) + (cb << 1)) ^ ((row & 7) << 4))) = kb4;
      float4 vf = vpre[e];
      *(__bf16*)(vsh + ((((cb + 0) << 7) + (row << 1)) ^ (((cb + 0) & 7) << 4))) = (__bf16)vf.x;
      *(__bf16*)(vsh + ((((cb + 1) << 7) + (row << 1)) ^ (((cb + 1) & 7) << 4))) = (__bf16)vf.y;
      *(__bf16*)(vsh + ((((cb + 2) << 7) + (row << 1)) ^ (((cb + 2) & 7) << 4))) = (__bf16)vf.z;
      *(__bf16*)(vsh + ((((cb + 3) << 7) + (row << 1)) ^ (((cb + 3) & 7) << 4))) = (__bf16)vf.w;
    }
    // keep current tile's softmax operands
    const float4 pc0 = ppre0, pc1 = ppre1, bc0 = bpre0, bc1 = bpre1;
    const uint4  mc0 = mq0,  mc1 = mq1;
    // ---- issue next tile's loads (stay in flight across raw barriers) ----
    if (tt + 1 < Tq) { issueKV(kv0 + KB); issuePB(kv0 + KB); }
    barw();
    // ---- phase 2: QK^T (wave: 16 rows x 32 cols) ----
#pragma unroll
    for (int cf = 0; cf < 2; ++cf) {
      f32x4 sacc = {0.f, 0.f, 0.f, 0.f};
      const int jcol = c0 + cf * 16 + llo;
#pragma unroll
      for (int ks = 0; ks < 2; ++ks) {
        const int d0 = ks * 32 + lhi * 8;
        bf16x8 bk = *(const bf16x8*)(ksh + (((jcol << 7) + (d0 << 1)) ^ ((jcol & 7) << 4)));
        sacc = __builtin_amdgcn_mfma_f32_16x16x32_bf16(aq[ks], bk, sacc, 0, 0, 0);
      }
      const int srow = r0 + lhi * 4;  // C layout: col=lane&15, row=(lane>>4)*4+reg
      ssh[(srow + 0) * SP + jcol] = sacc[0];
      ssh[(srow + 1) * SP + jcol] = sacc[1];
      ssh[(srow + 2) * SP + jcol] = sacc[2];
      ssh[(srow + 3) * SP + jcol] = sacc[3];
    }
    barw();
    // ---- phase 3: softmax: thread t owns row sr, cols sc..sc+7 ----
    {
      unsigned int mb[8];
      if (mask4) {
        mb[0] = mc0.x; mb[1] = mc0.y; mb[2] = mc0.z; mb[3] = mc0.w;
        mb[4] = mc1.x; mb[5] = mc1.y; mb[6] = mc1.z; mb[7] = mc1.w;
      } else {
        const unsigned int w0 = mc0.x, w1 = mc0.y;
        mb[0] = w0 & 0xffu; mb[1] = (w0 >> 8) & 0xffu;
        mb[2] = (w0 >> 16) & 0xffu; mb[3] = w0 >> 24;
        mb[4] = w1 & 0xffu; mb[5] = (w1 >> 8) & 0xffu;
        mb[6] = (w1 >> 16) & 0xffu; mb[7] = w1 >> 24;
      }
      float pa[8] = {pc0.x, pc0.y, pc0.z, pc0.w, pc1.x, pc1.y, pc1.z, pc1.w};
      float ba[8] = {bc0.x, bc0.y, bc0.z, bc0.w, bc1.x, bc1.y, bc1.z, bc1.w};
      float sv[8];
      float pmax = -FLT_MAX;
#pragma unroll
      for (int jj = 0; jj < 8; ++jj) {
        const int j = kv0 + sc + jj;
        float s = ssh[sr * SP + sc + jj] + pa[jj] + ba[jj];
        if (j > irow || mb[jj] == 0u) s = -FLT_MAX;
        sv[jj] = s;
        pmax = fmaxf(pmax, s);
      }
      pmax = fmaxf(pmax, __shfl_xor(pmax, 1));
      pmax = fmaxf(pmax, __shfl_xor(pmax, 2));
      pmax = fmaxf(pmax, __shfl_xor(pmax, 4));
      const float mnew = fmaxf(m_r, pmax);
      const float resc = __expf(m_r - mnew);  // exp(0)=1 when both -FLT_MAX
      float psum = 0.f;
      bf16x8 pb;
#pragma unroll
      for (int jj = 0; jj < 8; ++jj) {
        float p = __expf(sv[jj] - mnew);
        psum += p;
        pb[jj] = (__bf16)p;
      }
      *(bf16x8*)(psh + (((sr << 7) + (sc << 1)) ^ ((sr & 7) << 4))) = pb;
      psum += __shfl_xor(psum, 1);
      psum += __shfl_xor(psum, 2);
      psum += __shfl_xor(psum, 4);
      l_r = l_r * resc + psum;
      m_r = mnew;
      if ((t & 7) == 0) scale_s[sr] = resc;
    }
    barw();
    // ---- phase 4: rescale O and PV (wave's kv half: one K=32 step) ----
    {
      const int rbase = r0 + lhi * 4;
      const float f0s = scale_s[rbase + 0], f1s = scale_s[rbase + 1];
      const float f2s = scale_s[rbase + 2], f3s = scale_s[rbase + 3];
      const int prow = r0 + llo;
      const int pk   = c0 + lhi * 8;
      bf16x8 pfrag = *(const bf16x8*)(psh + (((prow << 7) + (pk << 1)) ^ ((prow & 7) << 4)));
#pragma unroll
      for (int df = 0; df < 4; ++df) {
        f32x4 oc = oacc[df];
        oc[0] *= f0s; oc[1] *= f1s; oc[2] *= f2s; oc[3] *= f3s;
        const int drow = df * 16 + llo;
        bf16x8 vfrag = *(const bf16x8*)(vsh + (((drow << 7) + (pk << 1)) ^ ((drow & 7) << 4)));
        oacc[df] = __builtin_amdgcn_mfma_f32_16x16x32_bf16(pfrag, vfrag, oc, 0, 0, 0);
      }
    }
    barw();
  } // kv tiles

  // ---- epilogue (no prefetch outstanding; full __syncthreads fine) ----
  if ((t & 7) == 0) { m_s[sr] = m_r; l_s[sr] = l_r; }
  const int anyNeed = __syncthreads_or(((t & 7) == 0) && (m_r == -FLT_MAX));
  if (anyNeed) {
    // fully-masked row(s): ref softmax is uniform over ALL 2048 -> col-mean of V
    if (t < DDIM) vmean_s[t] = 0.f;
    __syncthreads();
    {
      const int d = t & 63, part = t >> 6;
      float s = 0.f;
      for (int j = part; j < NN; j += 4) s += vg[((size_t)(h * NN + j)) * DDIM + d];
      atomicAdd(&vmean_s[d], s);
    }
    __syncthreads();
    if (t < DDIM) vmean_s[t] *= (1.0f / (float)NN);
    __syncthreads();
  }
  // combine the two kv-half partial accumulators via ssh
  if (w >= 2) {
    const int rbase = r0 + lhi * 4;
#pragma unroll
    for (int df = 0; df < 4; ++df) {
      const int d = df * 16 + llo;
      ssh[(rbase + 0) * SP + d] = oacc[df][0];
      ssh[(rbase + 1) * SP + d] = oacc[df][1];
      ssh[(rbase + 2) * SP + d] = oacc[df][2];
      ssh[(rbase + 3) * SP + d] = oacc[df][3];
    }
  }
  __syncthreads();
  if (w < 2) {
    const int rbase = r0 + lhi * 4;
#pragma unroll
    for (int df = 0; df < 4; ++df) {
      const int d = df * 16 + llo;
#pragma unroll
      for (int rr = 0; rr < 4; ++rr) {
        const int row = rbase + rr;
        const float val = oacc[df][rr] + ssh[row * SP + d];
        const float mm  = m_s[row];
        const float res = (mm == -FLT_MAX) ? vmean_s[d] : val / l_s[row];
        outg[((size_t)(h * NN) + qrow0 + row) * DDIM + d] = res;
      }
    }
  }
}

extern "C" void kernel_launch(void* const* d_in, const int* in_sizes, int n_in,
                              void* d_out, int out_size, void* d_ws, size_t ws_size,
                              hipStream_t stream) {
  (void)in_sizes; (void)n_in; (void)d_ws; (void)ws_size; (void)out_size;
  const float* q    = (const float*)d_in[0];
  const float* k    = (const float*)d_in[1];
  const float* v    = (const float*)d_in[2];
  const unsigned int* mask = (const unsigned int*)d_in[3];
  const float* bias = (const float*)d_in[4];
  const float* prev = (const float*)d_in[5];
  float* out = (float*)d_out;

  dim3 grid(64, HH);
  attend_fused<<<grid, 256, 0, stream>>>(q, k, v, mask, bias, prev, out);
}

// Round 4
// 219.403 us; speedup vs baseline: 1.7746x; 1.7746x over previous
//
#include <hip/hip_runtime.h>
#include <hip/hip_bf16.h>
#include <float.h>

#define NN 2048
#define HH 16
#define DDIM 64
#define QB 64   // q-rows per block = 4 waves x 16 rows
#define KB 64

typedef __bf16 bf16x8 __attribute__((ext_vector_type(8)));
typedef __bf16 bf16x4 __attribute__((ext_vector_type(4)));
typedef float f32x4 __attribute__((ext_vector_type(4)));

// Raw barrier: LDS-writes visible; outstanding GLOBAL prefetch loads stay in flight.
__device__ __forceinline__ void barw() {
  __builtin_amdgcn_sched_barrier(0);
  asm volatile("s_waitcnt lgkmcnt(0)" ::: "memory");
  __builtin_amdgcn_s_barrier();
  __builtin_amdgcn_sched_barrier(0);
}

__device__ __forceinline__ unsigned pack2(float a, float b) {
  union { __bf16 h[2]; unsigned u; } x;
  x.h[0] = (__bf16)a; x.h[1] = (__bf16)b;
  return x.u;
}

// R4: swapped-QK^T row-owning waves. Each wave owns 16 full q-rows; softmax
// entirely in-register (2 shuffles per reduce); P^T redistributed to the PV
// B-operand via 16 bpermutes. 2 barriers/tile (was 4). No S/P/scale LDS.
// S^T = mfma(A=K-frag,B=Q-frag): C col=llo -> q-row, row=lhi*4+reg -> kv.
// O^T = mfma(A=V^T-frag,B=P^T-frag): C col=llo -> q-row, row -> d.
__global__ __launch_bounds__(256, 2) void attend_fused(
    const float* __restrict__ qg, const float* __restrict__ kg,
    const float* __restrict__ vg, const unsigned int* __restrict__ maskw,
    const float* __restrict__ biasg, const float* __restrict__ prevg,
    float* __restrict__ outg)
{
  __shared__ char  ksh[KB * 128]   __attribute__((aligned(16))); // [kv][d] bf16, XOR-swizzled
  __shared__ char  vsh[DDIM * 128] __attribute__((aligned(16))); // [d][kv] bf16, XOR-swizzled
  __shared__ float vmean_s[DDIM];

  const int t    = threadIdx.x;
  const int lane = t & 63;
  const int w    = t >> 6;
  const int x    = blockIdx.x;
  const int h    = blockIdx.y;
  // causal balance: CU gets bids {c, c+256}; h differs by 8 -> complementary qt, sum=33 tiles.
  const int qt   = (h < 8) ? x : (31 - x);
  const int qrow0 = qt * QB;

  // --- mask element-width detection: 4-byte (int/float bool) vs 1-byte ---
  unsigned int mwrd = maskw[t & 255];
  const int mask4 = __syncthreads_and(mwrd == 0u || mwrd == 1u || mwrd == 0x3F800000u);

  const int llo = lane & 15;
  const int lhi = lane >> 4;
  const int qrow_g = qrow0 + w * 16 + llo;   // this lane's q-row (softmax + output)

  // --- Q fragments (B operand), scale 1/8 folded in ---
  bf16x8 aq[2];
  {
    const float* qp = qg + ((size_t)(h * NN + qrow_g)) * DDIM + lhi * 8;
#pragma unroll
    for (int ks = 0; ks < 2; ++ks) {
      float4 f0 = *(const float4*)(qp + ks * 32);
      float4 f1 = *(const float4*)(qp + ks * 32 + 4);
      bf16x8 a;
      a[0] = (__bf16)(f0.x * 0.125f); a[1] = (__bf16)(f0.y * 0.125f);
      a[2] = (__bf16)(f0.z * 0.125f); a[3] = (__bf16)(f0.w * 0.125f);
      a[4] = (__bf16)(f1.x * 0.125f); a[5] = (__bf16)(f1.y * 0.125f);
      a[6] = (__bf16)(f1.z * 0.125f); a[7] = (__bf16)(f1.w * 0.125f);
      aq[ks] = a;
    }
  }

  f32x4 oacc[4];   // O^T frags: oacc[df][r] = O[q=llo-row][d=df*16+lhi*4+r]
#pragma unroll
  for (int i = 0; i < 4; ++i) { f32x4 z = {0.f, 0.f, 0.f, 0.f}; oacc[i] = z; }
  float m_r = -FLT_MAX, l_r = 0.f;

  // ---- prefetch registers ----
  float4 kpre[4], vpre[4];
  float4 ppre[4], bpre[4];
  uint4  mpre[4];

  auto issueKV = [&](int kv0) {
#pragma unroll
    for (int e = 0; e < 4; ++e) {
      const int f4  = t + e * 256;
      const int row = f4 >> 4;
      const int cb  = (f4 & 15) * 4;
      const size_t gofs = ((size_t)(h * NN + kv0 + row)) * DDIM + cb;
      kpre[e] = *(const float4*)(kg + gofs);
      vpre[e] = *(const float4*)(vg + gofs);
    }
  };
  auto issuePB = [&](int kv0) {
#pragma unroll
    for (int kf = 0; kf < 4; ++kf) {
      const int col = kv0 + kf * 16 + lhi * 4;
      const size_t base = ((size_t)(h * NN) + qrow_g) * NN + col;
      ppre[kf] = *(const float4*)(prevg + base);
      bpre[kf] = *(const float4*)(biasg + base);
      const size_t midx = (size_t)qrow_g * NN + col;
      if (mask4) {
        mpre[kf] = *(const uint4*)(maskw + midx);
      } else {
        mpre[kf].x = *(const unsigned int*)((const unsigned char*)maskw + midx);
      }
    }
  };

  const int Tq = qt + 1;
  issueKV(0);
  issuePB(0);

  for (int tt = 0; tt < Tq; ++tt) {
    const int kv0 = tt * KB;
    // ---- phase 1: stage K (row-major) and V (transposed), f32->bf16, swizzled ----
#pragma unroll
    for (int e = 0; e < 4; ++e) {
      const int f4  = t + e * 256;
      const int row = f4 >> 4;
      const int cb  = (f4 & 15) * 4;
      float4 kf = kpre[e];
      bf16x4 kb4;
      kb4[0] = (__bf16)kf.x; kb4[1] = (__bf16)kf.y;
      kb4[2] = (__bf16)kf.z; kb4[3] = (__bf16)kf.w;
      *(bf16x4*)(ksh + (((row << 7) + (cb << 1)) ^ ((row & 7) << 4))) = kb4;
      float4 vf = vpre[e];
      *(__bf16*)(vsh + ((((cb + 0) << 7) + (row << 1)) ^ (((cb + 0) & 7) << 4))) = (__bf16)vf.x;
      *(__bf16*)(vsh + ((((cb + 1) << 7) + (row << 1)) ^ (((cb + 1) & 7) << 4))) = (__bf16)vf.y;
      *(__bf16*)(vsh + ((((cb + 2) << 7) + (row << 1)) ^ (((cb + 2) & 7) << 4))) = (__bf16)vf.z;
      *(__bf16*)(vsh + ((((cb + 3) << 7) + (row << 1)) ^ (((cb + 3) & 7) << 4))) = (__bf16)vf.w;
    }
    // keep current tile's softmax operands
    float4 pc[4], bc[4]; uint4 mc[4];
#pragma unroll
    for (int kf = 0; kf < 4; ++kf) { pc[kf] = ppre[kf]; bc[kf] = bpre[kf]; mc[kf] = mpre[kf]; }
    // issue next tile's loads (stay in flight across the raw barriers)
    if (tt + 1 < Tq) { issueKV(kv0 + KB); issuePB(kv0 + KB); }
    barw();

    // ---- QK^T swapped: S^T[kv][q], each lane: q=llo-row, 16 kv values ----
    f32x4 s[4];
#pragma unroll
    for (int kf = 0; kf < 4; ++kf) { f32x4 z = {0.f, 0.f, 0.f, 0.f}; s[kf] = z; }
#pragma unroll
    for (int ks = 0; ks < 2; ++ks) {
#pragma unroll
      for (int kf = 0; kf < 4; ++kf) {
        const int kvr = kf * 16 + llo;
        bf16x8 ak = *(const bf16x8*)(ksh + (((kvr << 7) + ((ks * 32 + lhi * 8) << 1)) ^ ((kvr & 7) << 4)));
        s[kf] = __builtin_amdgcn_mfma_f32_16x16x32_bf16(ak, aq[ks], s[kf], 0, 0, 0);
      }
    }

    // ---- softmax, fully in-register (row = q = llo; 4 lanes/row share via xor16/32) ----
    float p[4][4];
    float pmax = -FLT_MAX;
#pragma unroll
    for (int kf = 0; kf < 4; ++kf) {
      float pa[4] = {pc[kf].x, pc[kf].y, pc[kf].z, pc[kf].w};
      float ba[4] = {bc[kf].x, bc[kf].y, bc[kf].z, bc[kf].w};
      unsigned mb[4];
      if (mask4) { mb[0] = mc[kf].x; mb[1] = mc[kf].y; mb[2] = mc[kf].z; mb[3] = mc[kf].w; }
      else {
        mb[0] = mc[kf].x & 0xffu; mb[1] = (mc[kf].x >> 8) & 0xffu;
        mb[2] = (mc[kf].x >> 16) & 0xffu; mb[3] = mc[kf].x >> 24;
      }
#pragma unroll
      for (int r = 0; r < 4; ++r) {
        const int j = kv0 + kf * 16 + lhi * 4 + r;
        float sv = s[kf][r] + pa[r] + ba[r];
        if (j > qrow_g || mb[r] == 0u) sv = -FLT_MAX;
        p[kf][r] = sv;
        pmax = fmaxf(pmax, sv);
      }
    }
    pmax = fmaxf(pmax, __shfl_xor(pmax, 16));
    pmax = fmaxf(pmax, __shfl_xor(pmax, 32));
    const float mnew = fmaxf(m_r, pmax);
    const float resc = __expf(m_r - mnew);   // exp(0)=1 when both -FLT_MAX (finite)
    float psum = 0.f;
#pragma unroll
    for (int kf = 0; kf < 4; ++kf)
#pragma unroll
      for (int r = 0; r < 4; ++r) {
        float e = __expf(p[kf][r] - mnew);
        p[kf][r] = e;
        psum += e;
      }
    psum += __shfl_xor(psum, 16);
    psum += __shfl_xor(psum, 32);
    l_r = l_r * resc + psum;
    m_r = mnew;
#pragma unroll
    for (int df = 0; df < 4; ++df) {
      oacc[df][0] *= resc; oacc[df][1] *= resc;
      oacc[df][2] *= resc; oacc[df][3] *= resc;
    }

    // ---- pack P -> bf16 pairs; redistribute P^T into PV B-operand; PV MFMAs ----
    unsigned U[4][2];
#pragma unroll
    for (int kf = 0; kf < 4; ++kf) {
      U[kf][0] = pack2(p[kf][0], p[kf][1]);
      U[kf][1] = pack2(p[kf][2], p[kf][3]);
    }
#pragma unroll
    for (int ks = 0; ks < 2; ++ks) {
      unsigned bb[4];
#pragma unroll
      for (int m = 0; m < 4; ++m) {
        // dst lane needs kv pair p = ks*16 + lhi*4 + m (u32 granules) of its q-row.
        // src lane: same llo, lhi_src = (lhi&1)*2 + (m>>1); frag = 2ks + (lhi>>1); half = m&1.
        const int src = llo + ((((lhi & 1) << 1) + (m >> 1)) << 4);
        const int va = __shfl((int)U[2 * ks + 0][m & 1], src);
        const int vb = __shfl((int)U[2 * ks + 1][m & 1], src);
        bb[m] = (lhi >> 1) ? (unsigned)vb : (unsigned)va;
      }
      union { unsigned u[4]; bf16x8 v; } pb_;
      pb_.u[0] = bb[0]; pb_.u[1] = bb[1]; pb_.u[2] = bb[2]; pb_.u[3] = bb[3];
#pragma unroll
      for (int df = 0; df < 4; ++df) {
        const int dr = df * 16 + llo;
        bf16x8 vf = *(const bf16x8*)(vsh + (((dr << 7) + ((ks * 32 + lhi * 8) << 1)) ^ ((dr & 7) << 4)));
        oacc[df] = __builtin_amdgcn_mfma_f32_16x16x32_bf16(vf, pb_.v, oacc[df], 0, 0, 0);
      }
    }
    barw();   // all waves done reading ksh/vsh before next staging overwrite
  } // kv tiles

  // ---- epilogue: each wave owns its rows; no cross-wave combine ----
  const int anyNeed = __syncthreads_or(m_r == -FLT_MAX);
  if (anyNeed) {
    // fully-masked row: ref softmax uniform over ALL 2048 -> column mean of V
    if (t < DDIM) vmean_s[t] = 0.f;
    __syncthreads();
    {
      const int d = t & 63, part = t >> 6;
      float sacc = 0.f;
      for (int j = part; j < NN; j += 4) sacc += vg[((size_t)(h * NN + j)) * DDIM + d];
      atomicAdd(&vmean_s[d], sacc);
    }
    __syncthreads();
    if (t < DDIM) vmean_s[t] *= (1.0f / (float)NN);
    __syncthreads();
  }
  const float invl = 1.0f / l_r;
  const bool dead = (m_r == -FLT_MAX);
#pragma unroll
  for (int df = 0; df < 4; ++df) {
    const int dbase = df * 16 + lhi * 4;
    float4 o;
    o.x = dead ? vmean_s[dbase + 0] : oacc[df][0] * invl;
    o.y = dead ? vmean_s[dbase + 1] : oacc[df][1] * invl;
    o.z = dead ? vmean_s[dbase + 2] : oacc[df][2] * invl;
    o.w = dead ? vmean_s[dbase + 3] : oacc[df][3] * invl;
    *(float4*)(outg + ((size_t)(h * NN) + qrow_g) * DDIM + dbase) = o;
  }
}

extern "C" void kernel_launch(void* const* d_in, const int* in_sizes, int n_in,
                              void* d_out, int out_size, void* d_ws, size_t ws_size,
                              hipStream_t stream) {
  (void)in_sizes; (void)n_in; (void)d_ws; (void)ws_size; (void)out_size;
  const float* q    = (const float*)d_in[0];
  const float* k    = (const float*)d_in[1];
  const float* v    = (const float*)d_in[2];
  const unsigned int* mask = (const unsigned int*)d_in[3];
  const float* bias = (const float*)d_in[4];
  const float* prev = (const float*)d_in[5];
  float* out = (float*)d_out;

  dim3 grid(32, HH);
  attend_fused<<<grid, 256, 0, stream>>>(q, k, v, mask, bias, prev, out);
}